// Round 12
// baseline (197.437 us; speedup 1.0000x reference)
//
#include <hip/hip_runtime.h>

#define DIMC   512
#define NHEADS 8
#define HDIM   64
#define DD     6
#define HHH    48
#define WWW    96
#define NPOS   (DD * HHH * WWW)   // 27648

typedef unsigned short u16;
typedef __attribute__((ext_vector_type(8))) short bf16x8;
typedef __attribute__((ext_vector_type(4))) float f32x4;

static __device__ __forceinline__ float b2f(u16 u) {
    return __builtin_bit_cast(float, (unsigned)u << 16);
}
static __device__ __forceinline__ u16 f2b(float f) {
    unsigned x = __builtin_bit_cast(unsigned, f);
    return (u16)((x + 0x7fffu + ((x >> 16) & 1u)) >> 16);
}

static __device__ __forceinline__ void gload_lds16(const void* g, void* l) {
    __builtin_amdgcn_global_load_lds((const __attribute__((address_space(1))) void*)g,
                                     (__attribute__((address_space(3))) void*)l, 16, 0, 0);
}

// ---------------------------------------------------------------------------
// converts (known-good; cvt_x measured at HBM roofline ~6.5 TB/s)
// ---------------------------------------------------------------------------
__global__ __launch_bounds__(256) void cvt_x_bf16(const float* __restrict__ in,
                                                  u16* __restrict__ out, int n4) {
    const int i = blockIdx.x * 256 + threadIdx.x;
    float4 v = reinterpret_cast<const float4*>(in)[i];
    ushort4 o = { f2b(v.x), f2b(v.y), f2b(v.z), f2b(v.w) };
    reinterpret_cast<ushort4*>(out)[i] = o;
}

__global__ __launch_bounds__(256) void cvt_wqkvT(const float* __restrict__ w,
                                                 u16* __restrict__ o) {
    const int id = blockIdx.x * 256 + threadIdx.x;
    const int nn = id >> 9, kk = id & 511;
    o[id] = f2b(w[(size_t)kk * 1536 + nn]);
}

__global__ __launch_bounds__(256) void cvt_wprojT(const float* __restrict__ w,
                                                  u16* __restrict__ o) {
    const int id = blockIdx.x * 256 + threadIdx.x;   // 512*512 exact
    const int nn = id >> 9, kk = id & 511;
    o[id] = f2b(w[(size_t)kk * 512 + nn]);
}

// ---------------------------------------------------------------------------
// bf16 MFMA GEMM — R8/R11 structure + hoisted K-loop addressing (R12).
// 128x128 tile, BK=32, 4 waves; LDS chunk swizzle g^((row>>1)&3) (measured
// 0 conflicts); XCD-aware grid. R11 counters showed VALUBusy 46% vs MfmaUtil
// 23%: the K-loop recomputed four 64-bit addresses (mul-add chain) per step.
// Now: pointers hoisted, +32 elems/step increments; dead kwrap removed.
// Bit-identical arithmetic.
// ---------------------------------------------------------------------------
__global__ __launch_bounds__(256) void gemm_bf16_mfma(
    const u16* __restrict__ A, int lda,
    const u16* __restrict__ B, int ldb,
    const float* __restrict__ bias, int Kp,
    void* __restrict__ Cout, int ldc, int cmode, int nx)
{
    __shared__ u16 As[128 * 32];
    __shared__ u16 Bs[128 * 32];

    const int tid = threadIdx.x;
    const int l   = tid & 63;
    const int w   = tid >> 6;
    const int wr  = w >> 1, wc = w & 1;

    // XCD swizzle: gridDim.x % 8 == 0 guaranteed by launch shapes
    const int cpx = gridDim.x >> 3;
    const int idp = (blockIdx.x & 7) * cpx + (blockIdx.x >> 3);
    const int by  = idp / nx;
    const int bx  = idp - by * nx;
    const int m0  = by * 128;
    const int n0  = bx * 128;

    // staging: physical slot (srow, tid&3) <- global logical col-group
    // (tid&3) ^ ((srow>>1)&3)  [inverse swizzle on source, LDS dest linear]
    const int srow = tid >> 2;
    const int scol = ((tid & 3) ^ ((tid >> 3) & 3)) * 8;

    // hoisted global pointers (incremented by +32 elems per K-step)
    const u16* ga = A + (size_t)(m0 + srow) * lda + scol;
    const u16* gb = B + (size_t)(n0 + srow) * ldb + scol;
    const size_t a64 = (size_t)64 * lda;
    const size_t b64 = (size_t)64 * ldb;
    // hoisted LDS destinations
    u16* const la0 = As + w * 512;
    u16* const la1 = As + 2048 + w * 512;
    u16* const lb0 = Bs + w * 512;
    u16* const lb1 = Bs + 2048 + w * 512;

    f32x4 acc[4][4];
#pragma unroll
    for (int i = 0; i < 4; i++)
#pragma unroll
        for (int j = 0; j < 4; j++) acc[i][j] = (f32x4)0.0f;

    const int lrow = l & 15;
    // read swizzle: (row>>1)&3 == (lrow>>1)&3 (frag row bases are mult of 16)
    const int lk   = (((l >> 4) ^ ((lrow >> 1) & 3))) * 8;

#pragma unroll 1
    for (int k0 = 0; k0 < Kp; k0 += 32) {
        gload_lds16(ga,       la0);
        gload_lds16(ga + a64, la1);
        gload_lds16(gb,       lb0);
        gload_lds16(gb + b64, lb1);
        ga += 32; gb += 32;
        __syncthreads();

        bf16x8 af[4], bfr[4];
#pragma unroll
        for (int f = 0; f < 4; f++) {
            af[f]  = *reinterpret_cast<const bf16x8*>(&As[(wr * 64 + f * 16 + lrow) * 32 + lk]);
            bfr[f] = *reinterpret_cast<const bf16x8*>(&Bs[(wc * 64 + f * 16 + lrow) * 32 + lk]);
        }
#pragma unroll
        for (int i = 0; i < 4; i++)
#pragma unroll
            for (int j = 0; j < 4; j++)
                acc[i][j] = __builtin_amdgcn_mfma_f32_16x16x32_bf16(af[i], bfr[j], acc[i][j], 0, 0, 0);
        __syncthreads();
    }

#pragma unroll
    for (int i = 0; i < 4; i++) {
        const int mb = m0 + wr * 64 + i * 16 + (l >> 4) * 4;
#pragma unroll
        for (int j = 0; j < 4; j++) {
            const int n = n0 + wc * 64 + j * 16 + lrow;
            const float bv = bias[n];
#pragma unroll
            for (int r = 0; r < 4; r++) {
                const float v = acc[i][j][r] + bv;
                if (cmode) reinterpret_cast<u16*>(Cout)[(size_t)(mb + r) * ldc + n] = f2b(v);
                else       reinterpret_cast<float*>(Cout)[(size_t)(mb + r) * ldc + n] = v;
            }
        }
    }
}

// ---------------------------------------------------------------------------
// MFMA neighborhood attention, 1x4x4 position tiles (R8/R11 known-good).
// ---------------------------------------------------------------------------
__global__ __launch_bounds__(512, 4) void na3d_mfma(
    const u16* __restrict__ qkv, u16* __restrict__ attnc)
{
    __shared__ int   rowoff[192];
    __shared__ int   dlt[16];
    __shared__ u16   Pbuf[NHEADS][16][36];
    __shared__ u16   Vt[NHEADS][64][36];
    __shared__ float ssum_lds[NHEADS][16];

    const int bid  = blockIdx.x;
    const int tile = (bid & 7) * 216 + (bid >> 3);
    const int pd  = tile / 288;
    const int rem = tile - pd * 288;
    const int h0  = (rem / 24) * 4;
    const int w0  = (rem % 24) * 4;
    const int sd  = min(max(pd - 1, 0), DD - 3);
    const int shb = min(max(h0 - 2, 0), HHH - 5);
    const int swb = min(max(w0 - 2, 0), WWW - 5);

    const int tid = threadIdx.x;
    if (tid < 192) {
        const int dd = tid >> 6, hh = (tid >> 3) & 7, wu = tid & 7;
        const int row = (sd + dd) * (HHH * WWW)
                      + min(shb + hh, HHH - 1) * WWW + min(swb + wu, WWW - 1);
        rowoff[tid] = row * 1536;
    }
    if (tid < 16) {
        const int ph = h0 + (tid >> 2), pw = w0 + (tid & 3);
        const int dh = min(max(ph - 2, 0), HHH - 5) - shb;
        const int dw = min(max(pw - 2, 0), WWW - 5) - swb;
        dlt[tid] = (dh << 4) | dw;
    }
    __syncthreads();

    const int head = tid >> 6;
    const int l    = tid & 63;
    const int g    = l >> 4;
    const int c    = l & 15;

    const int qrowi = pd * (HHH * WWW) + (h0 + (c >> 2)) * WWW + (w0 + (c & 3));
    const u16* qrow = qkv + (size_t)qrowi * 1536 + head * HDIM;
    const bf16x8 qlo = *reinterpret_cast<const bf16x8*>(qrow + 8 * g);
    const bf16x8 qhi = *reinterpret_cast<const bf16x8*>(qrow + 32 + 8 * g);
    const int dparts = dlt[c];
    const int dh = dparts >> 4, dw = dparts & 15;

    f32x4 oacc[4];
#pragma unroll
    for (int j = 0; j < 4; j++) oacc[j] = (f32x4)0.0f;
    float ssum = 0.0f;

    const float SC = 0.022542110f;   // log2(e)/64

#pragma unroll 1
    for (int s = 0; s < 6; ++s) {
        {
            const int npair = l >> 2;
            const int chq   = l & 3;
#pragma unroll
            for (int rr = 0; rr < 2; ++rr) {
                const int ch8 = 8 * chq + 32 * rr;
                const int2 rp = *reinterpret_cast<const int2*>(&rowoff[s * 32 + 2 * npair]);
                const ushort4* pa = reinterpret_cast<const ushort4*>(qkv + rp.x + 1024 + head * HDIM + ch8);
                const ushort4* pb = reinterpret_cast<const ushort4*>(qkv + rp.y + 1024 + head * HDIM + ch8);
                ushort4 va0 = pa[0], va1 = pa[1];
                ushort4 vb0 = pb[0], vb1 = pb[1];
                const u16* va = reinterpret_cast<const u16*>(&va0);
                const u16* vb = reinterpret_cast<const u16*>(&vb0);
#pragma unroll
                for (int e = 0; e < 4; ++e) {
                    unsigned dwo = (unsigned)va[e] | ((unsigned)vb[e] << 16);
                    *reinterpret_cast<unsigned*>(&Vt[head][ch8 + e][2 * npair]) = dwo;
                }
                const u16* va2 = reinterpret_cast<const u16*>(&va1);
                const u16* vb2 = reinterpret_cast<const u16*>(&vb1);
#pragma unroll
                for (int e = 0; e < 4; ++e) {
                    unsigned dwo = (unsigned)va2[e] | ((unsigned)vb2[e] << 16);
                    *reinterpret_cast<unsigned*>(&Vt[head][ch8 + 4 + e][2 * npair]) = dwo;
                }
            }
        }

#pragma unroll
        for (int t = 0; t < 2; ++t) {
            const int sb0 = s * 32 + t * 16;
            const int ro  = rowoff[sb0 + c];
            const u16* kr = qkv + ro + 512 + head * HDIM;
            const bf16x8 klo = *reinterpret_cast<const bf16x8*>(kr + 8 * g);
            const bf16x8 khi = *reinterpret_cast<const bf16x8*>(kr + 32 + 8 * g);
            f32x4 sf = (f32x4)0.0f;
            sf = __builtin_amdgcn_mfma_f32_16x16x32_bf16(klo, qlo, sf, 0, 0, 0);
            sf = __builtin_amdgcn_mfma_f32_16x16x32_bf16(khi, qhi, sf, 0, 0, 0);
            const int sb  = sb0 + 4 * g;
            const int wu0 = sb & 7;
            const int hh_ = (sb >> 3) & 7;
            const bool hv = ((unsigned)(hh_ - dh) < 5u);
            float e0, e1, e2, e3;
            e0 = (hv && (unsigned)(wu0 + 0 - dw) < 5u) ? exp2f(sf[0] * SC) : 0.0f;
            e1 = (hv && (unsigned)(wu0 + 1 - dw) < 5u) ? exp2f(sf[1] * SC) : 0.0f;
            e2 = (hv && (unsigned)(wu0 + 2 - dw) < 5u) ? exp2f(sf[2] * SC) : 0.0f;
            e3 = (hv && (unsigned)(wu0 + 3 - dw) < 5u) ? exp2f(sf[3] * SC) : 0.0f;
            ssum += e0 + e1 + e2 + e3;
            const unsigned p01 = (unsigned)f2b(e0) | ((unsigned)f2b(e1) << 16);
            const unsigned p23 = (unsigned)f2b(e2) | ((unsigned)f2b(e3) << 16);
            *reinterpret_cast<unsigned*>(&Pbuf[head][c][t * 16 + 4 * g])     = p01;
            *reinterpret_cast<unsigned*>(&Pbuf[head][c][t * 16 + 4 * g + 2]) = p23;
        }

        {
            const uint2 p01 = *reinterpret_cast<const uint2*>(&Pbuf[head][c][8 * g]);
            const uint2 p23 = *reinterpret_cast<const uint2*>(&Pbuf[head][c][8 * g + 4]);
            const int4 pv = make_int4((int)p01.x, (int)p01.y, (int)p23.x, (int)p23.y);
            const bf16x8 pfrag = __builtin_bit_cast(bf16x8, pv);
#pragma unroll
            for (int j = 0; j < 4; ++j) {
                const uint2 v01 = *reinterpret_cast<const uint2*>(&Vt[head][16 * j + c][8 * g]);
                const uint2 v23 = *reinterpret_cast<const uint2*>(&Vt[head][16 * j + c][8 * g + 4]);
                const int4 vv = make_int4((int)v01.x, (int)v01.y, (int)v23.x, (int)v23.y);
                const bf16x8 vfrag = __builtin_bit_cast(bf16x8, vv);
                oacc[j] = __builtin_amdgcn_mfma_f32_16x16x32_bf16(pfrag, vfrag, oacc[j], 0, 0, 0);
            }
        }
    }

    ssum += __shfl_xor(ssum, 16);
    ssum += __shfl_xor(ssum, 32);
    if (l < 16) ssum_lds[head][c] = ssum;
    const f32x4 sums4 = *reinterpret_cast<const f32x4*>(&ssum_lds[head][4 * g]);

    const int orow = pd * (HHH * WWW) + (h0 + g) * WWW + w0;
#pragma unroll
    for (int r = 0; r < 4; ++r) {
        const float inv = 1.0f / sums4[r];
        u16* base = attnc + (size_t)(orow + r) * 512 + head * HDIM;
#pragma unroll
        for (int j = 0; j < 4; ++j)
            base[16 * j + c] = f2b(oacc[j][r] * inv);
    }
}

// ---------------------------------------------------------------------------
extern "C" void kernel_launch(void* const* d_in, const int* in_sizes, int n_in,
                              void* d_out, int out_size, void* d_ws, size_t ws_size,
                              hipStream_t stream)
{
    const float* x      = (const float*)d_in[0];
    const float* w_qkv  = (const float*)d_in[1];
    const float* b_qkv  = (const float*)d_in[2];
    const float* w_proj = (const float*)d_in[3];
    const float* b_proj = (const float*)d_in[4];
    float* out = (float*)d_out;

    u16* qkvb   = (u16*)d_ws;                         // [27648][1536]
    u16* attnc  = qkvb  + (size_t)NPOS * 1536;        // [27648][512] bf16
    u16* xb     = attnc + (size_t)NPOS * 512;         // [27648][512]
    u16* wqkvT  = xb    + (size_t)NPOS * 512;         // [1536][512]
    u16* wprojT = wqkvT + (size_t)1536 * 512;         // [512][512]

    cvt_x_bf16<<<(NPOS * 512 / 4) / 256, 256, 0, stream>>>(x, xb, NPOS * 512 / 4);
    cvt_wqkvT<<<(1536 * 512) / 256, 256, 0, stream>>>(w_qkv, wqkvT);
    cvt_wprojT<<<(512 * 512) / 256, 256, 0, stream>>>(w_proj, wprojT);

    // 1) qkv = x @ w_qkv + b_qkv  (bf16, K=512); grid 2592 = 8*324, nx=12
    gemm_bf16_mfma<<<(1536 / 128) * (NPOS / 128), 256, 0, stream>>>(
        xb, 512, wqkvT, 512, b_qkv, 512, qkvb, 1536, 1, 1536 / 128);

    // 2) attention -> bf16 [NPOS][512]
    na3d_mfma<<<NPOS / 16, 512, 0, stream>>>(qkvb, attnc);

    // 3) out = attn @ w_proj + b_proj  (bf16, K=512); grid 864 = 8*108, nx=4
    gemm_bf16_mfma<<<(512 / 128) * (NPOS / 128), 256, 0, stream>>>(
        attnc, 512, wprojT, 512, b_proj, 512, out, 512, 0, 512 / 128);
}

// Round 13
// 186.671 us; speedup vs baseline: 1.0577x; 1.0577x over previous
//
#include <hip/hip_runtime.h>

#define DIMC   512
#define NHEADS 8
#define HDIM   64
#define DD     6
#define HHH    48
#define WWW    96
#define NPOS   (DD * HHH * WWW)   // 27648

typedef unsigned short u16;
typedef __attribute__((ext_vector_type(8))) short bf16x8;
typedef __attribute__((ext_vector_type(4))) float f32x4;

static __device__ __forceinline__ float b2f(u16 u) {
    return __builtin_bit_cast(float, (unsigned)u << 16);
}
static __device__ __forceinline__ u16 f2b(float f) {
    unsigned x = __builtin_bit_cast(unsigned, f);
    return (u16)((x + 0x7fffu + ((x >> 16) & 1u)) >> 16);
}

static __device__ __forceinline__ void gload_lds16(const void* g, void* l) {
    __builtin_amdgcn_global_load_lds((const __attribute__((address_space(1))) void*)g,
                                     (__attribute__((address_space(3))) void*)l, 16, 0, 0);
}

// ---------------------------------------------------------------------------
// converts (known-good)
// ---------------------------------------------------------------------------
__global__ __launch_bounds__(256) void cvt_x_bf16(const float* __restrict__ in,
                                                  u16* __restrict__ out, int n4) {
    const int i = blockIdx.x * 256 + threadIdx.x;
    float4 v = reinterpret_cast<const float4*>(in)[i];
    ushort4 o = { f2b(v.x), f2b(v.y), f2b(v.z), f2b(v.w) };
    reinterpret_cast<ushort4*>(out)[i] = o;
}

__global__ __launch_bounds__(256) void cvt_wqkvT(const float* __restrict__ w,
                                                 u16* __restrict__ o) {
    const int id = blockIdx.x * 256 + threadIdx.x;
    const int nn = id >> 9, kk = id & 511;
    o[id] = f2b(w[(size_t)kk * 1536 + nn]);
}

__global__ __launch_bounds__(256) void cvt_wprojT(const float* __restrict__ w,
                                                  u16* __restrict__ o) {
    const int id = blockIdx.x * 256 + threadIdx.x;   // 512*512 exact
    const int nn = id >> 9, kk = id & 511;
    o[id] = f2b(w[(size_t)kk * 512 + nn]);
}

// ---------------------------------------------------------------------------
// bf16 MFMA GEMM — R8 structure with BK=64 (R13).
// 128x128 tile, 4 waves, K-step 64: 8 steps for K=512 (vs 16) -> half the
// vmcnt(0)+barrier drain events (the m97-structure's ~20% stall). Staging:
// 8 gload_lds/thread/step, LDS 2x16 KB rows of 64 elems (128 B).
// Swizzle (rule 21, involution chunk^=(row&7)): linear LDS dest, source col
// pre-swizzled (t&7)^((t>>3)&7), frag-read chunk (4h+g)^(c&7) — per-lane
// constant; 16-lane residues all distinct -> 2-way (free). K-order of the
// two 32-halves preserved -> bit-identical results vs BK=32.
// XCD-aware grid swizzle unchanged.
// ---------------------------------------------------------------------------
__global__ __launch_bounds__(256) void gemm_bf16_mfma(
    const u16* __restrict__ A, int lda,
    const u16* __restrict__ B, int ldb,
    const float* __restrict__ bias, int Kp,
    void* __restrict__ Cout, int ldc, int cmode, int nx)
{
    __shared__ u16 As[128 * 64];
    __shared__ u16 Bs[128 * 64];

    const int tid = threadIdx.x;
    const int l   = tid & 63;
    const int w   = tid >> 6;
    const int wr  = w >> 1, wc = w & 1;

    // XCD swizzle: gridDim.x % 8 == 0 guaranteed by launch shapes
    const int cpx = gridDim.x >> 3;
    const int idp = (blockIdx.x & 7) * cpx + (blockIdx.x >> 3);
    const int by  = idp / nx;
    const int bx  = idp - by * nx;
    const int m0  = by * 128;
    const int n0  = bx * 128;

    // staging map: thread t -> row (t>>3) + 32*round, phys chunk t&7.
    // source column carries the inverse swizzle: (t&7) ^ ((t>>3)&7).
    const int srow = tid >> 3;                        // 0..31
    const int schk = ((tid & 7) ^ (srow & 7)) * 8;    // source col elems

    // hoisted global pointers (advance +64 elems per K-step)
    const u16* ga = A + (size_t)(m0 + srow) * lda + schk;
    const u16* gb = B + (size_t)(n0 + srow) * ldb + schk;
    const size_t a32 = (size_t)32 * lda;
    const size_t b32 = (size_t)32 * ldb;
    // wave-uniform LDS bases: wave w, round q covers rows q*32 + w*8 .. +8
    u16* const la0 = As + (w * 8) * 64;
    u16* const lb0 = Bs + (w * 8) * 64;

    f32x4 acc[4][4];
#pragma unroll
    for (int i = 0; i < 4; i++)
#pragma unroll
        for (int j = 0; j < 4; j++) acc[i][j] = (f32x4)0.0f;

    const int c   = l & 15;
    const int g   = l >> 4;
    // frag-read chunk offsets (per-lane constants), k-half 0 and 1
    const int lk0 = (((0 * 4 + g) ^ (c & 7))) * 8;
    const int lk1 = (((1 * 4 + g) ^ (c & 7))) * 8;

#pragma unroll 1
    for (int k0 = 0; k0 < Kp; k0 += 64) {
#pragma unroll
        for (int q = 0; q < 4; ++q) {
            gload_lds16(ga + q * a32, la0 + q * 32 * 64);
            gload_lds16(gb + q * b32, lb0 + q * 32 * 64);
        }
        ga += 64; gb += 64;
        __syncthreads();

        // k-half 0 (k0..k0+31)
        {
            bf16x8 af[4], bfr[4];
#pragma unroll
            for (int f = 0; f < 4; f++) {
                af[f]  = *reinterpret_cast<const bf16x8*>(&As[(wr * 64 + f * 16 + c) * 64 + lk0]);
                bfr[f] = *reinterpret_cast<const bf16x8*>(&Bs[(wc * 64 + f * 16 + c) * 64 + lk0]);
            }
#pragma unroll
            for (int i = 0; i < 4; i++)
#pragma unroll
                for (int j = 0; j < 4; j++)
                    acc[i][j] = __builtin_amdgcn_mfma_f32_16x16x32_bf16(af[i], bfr[j], acc[i][j], 0, 0, 0);
        }
        // k-half 1 (k0+32..k0+63)
        {
            bf16x8 af[4], bfr[4];
#pragma unroll
            for (int f = 0; f < 4; f++) {
                af[f]  = *reinterpret_cast<const bf16x8*>(&As[(wr * 64 + f * 16 + c) * 64 + lk1]);
                bfr[f] = *reinterpret_cast<const bf16x8*>(&Bs[(wc * 64 + f * 16 + c) * 64 + lk1]);
            }
#pragma unroll
            for (int i = 0; i < 4; i++)
#pragma unroll
                for (int j = 0; j < 4; j++)
                    acc[i][j] = __builtin_amdgcn_mfma_f32_16x16x32_bf16(af[i], bfr[j], acc[i][j], 0, 0, 0);
        }
        __syncthreads();
    }

#pragma unroll
    for (int i = 0; i < 4; i++) {
        const int mb = m0 + wr * 64 + i * 16 + g * 4;
#pragma unroll
        for (int j = 0; j < 4; j++) {
            const int n = n0 + wc * 64 + j * 16 + c;
            const float bv = bias[n];
#pragma unroll
            for (int r = 0; r < 4; r++) {
                const float v = acc[i][j][r] + bv;
                if (cmode) reinterpret_cast<u16*>(Cout)[(size_t)(mb + r) * ldc + n] = f2b(v);
                else       reinterpret_cast<float*>(Cout)[(size_t)(mb + r) * ldc + n] = v;
            }
        }
    }
}

// ---------------------------------------------------------------------------
// MFMA neighborhood attention, 1x4x4 position tiles (R8/R11 known-good).
// ---------------------------------------------------------------------------
__global__ __launch_bounds__(512, 4) void na3d_mfma(
    const u16* __restrict__ qkv, u16* __restrict__ attnc)
{
    __shared__ int   rowoff[192];
    __shared__ int   dlt[16];
    __shared__ u16   Pbuf[NHEADS][16][36];
    __shared__ u16   Vt[NHEADS][64][36];
    __shared__ float ssum_lds[NHEADS][16];

    const int bid  = blockIdx.x;
    const int tile = (bid & 7) * 216 + (bid >> 3);
    const int pd  = tile / 288;
    const int rem = tile - pd * 288;
    const int h0  = (rem / 24) * 4;
    const int w0  = (rem % 24) * 4;
    const int sd  = min(max(pd - 1, 0), DD - 3);
    const int shb = min(max(h0 - 2, 0), HHH - 5);
    const int swb = min(max(w0 - 2, 0), WWW - 5);

    const int tid = threadIdx.x;
    if (tid < 192) {
        const int dd = tid >> 6, hh = (tid >> 3) & 7, wu = tid & 7;
        const int row = (sd + dd) * (HHH * WWW)
                      + min(shb + hh, HHH - 1) * WWW + min(swb + wu, WWW - 1);
        rowoff[tid] = row * 1536;
    }
    if (tid < 16) {
        const int ph = h0 + (tid >> 2), pw = w0 + (tid & 3);
        const int dh = min(max(ph - 2, 0), HHH - 5) - shb;
        const int dw = min(max(pw - 2, 0), WWW - 5) - swb;
        dlt[tid] = (dh << 4) | dw;
    }
    __syncthreads();

    const int head = tid >> 6;
    const int l    = tid & 63;
    const int g    = l >> 4;
    const int c    = l & 15;

    const int qrowi = pd * (HHH * WWW) + (h0 + (c >> 2)) * WWW + (w0 + (c & 3));
    const u16* qrow = qkv + (size_t)qrowi * 1536 + head * HDIM;
    const bf16x8 qlo = *reinterpret_cast<const bf16x8*>(qrow + 8 * g);
    const bf16x8 qhi = *reinterpret_cast<const bf16x8*>(qrow + 32 + 8 * g);
    const int dparts = dlt[c];
    const int dh = dparts >> 4, dw = dparts & 15;

    f32x4 oacc[4];
#pragma unroll
    for (int j = 0; j < 4; j++) oacc[j] = (f32x4)0.0f;
    float ssum = 0.0f;

    const float SC = 0.022542110f;   // log2(e)/64

#pragma unroll 1
    for (int s = 0; s < 6; ++s) {
        {
            const int npair = l >> 2;
            const int chq   = l & 3;
#pragma unroll
            for (int rr = 0; rr < 2; ++rr) {
                const int ch8 = 8 * chq + 32 * rr;
                const int2 rp = *reinterpret_cast<const int2*>(&rowoff[s * 32 + 2 * npair]);
                const ushort4* pa = reinterpret_cast<const ushort4*>(qkv + rp.x + 1024 + head * HDIM + ch8);
                const ushort4* pb = reinterpret_cast<const ushort4*>(qkv + rp.y + 1024 + head * HDIM + ch8);
                ushort4 va0 = pa[0], va1 = pa[1];
                ushort4 vb0 = pb[0], vb1 = pb[1];
                const u16* va = reinterpret_cast<const u16*>(&va0);
                const u16* vb = reinterpret_cast<const u16*>(&vb0);
#pragma unroll
                for (int e = 0; e < 4; ++e) {
                    unsigned dwo = (unsigned)va[e] | ((unsigned)vb[e] << 16);
                    *reinterpret_cast<unsigned*>(&Vt[head][ch8 + e][2 * npair]) = dwo;
                }
                const u16* va2 = reinterpret_cast<const u16*>(&va1);
                const u16* vb2 = reinterpret_cast<const u16*>(&vb1);
#pragma unroll
                for (int e = 0; e < 4; ++e) {
                    unsigned dwo = (unsigned)va2[e] | ((unsigned)vb2[e] << 16);
                    *reinterpret_cast<unsigned*>(&Vt[head][ch8 + 4 + e][2 * npair]) = dwo;
                }
            }
        }

#pragma unroll
        for (int t = 0; t < 2; ++t) {
            const int sb0 = s * 32 + t * 16;
            const int ro  = rowoff[sb0 + c];
            const u16* kr = qkv + ro + 512 + head * HDIM;
            const bf16x8 klo = *reinterpret_cast<const bf16x8*>(kr + 8 * g);
            const bf16x8 khi = *reinterpret_cast<const bf16x8*>(kr + 32 + 8 * g);
            f32x4 sf = (f32x4)0.0f;
            sf = __builtin_amdgcn_mfma_f32_16x16x32_bf16(klo, qlo, sf, 0, 0, 0);
            sf = __builtin_amdgcn_mfma_f32_16x16x32_bf16(khi, qhi, sf, 0, 0, 0);
            const int sb  = sb0 + 4 * g;
            const int wu0 = sb & 7;
            const int hh_ = (sb >> 3) & 7;
            const bool hv = ((unsigned)(hh_ - dh) < 5u);
            float e0, e1, e2, e3;
            e0 = (hv && (unsigned)(wu0 + 0 - dw) < 5u) ? exp2f(sf[0] * SC) : 0.0f;
            e1 = (hv && (unsigned)(wu0 + 1 - dw) < 5u) ? exp2f(sf[1] * SC) : 0.0f;
            e2 = (hv && (unsigned)(wu0 + 2 - dw) < 5u) ? exp2f(sf[2] * SC) : 0.0f;
            e3 = (hv && (unsigned)(wu0 + 3 - dw) < 5u) ? exp2f(sf[3] * SC) : 0.0f;
            ssum += e0 + e1 + e2 + e3;
            const unsigned p01 = (unsigned)f2b(e0) | ((unsigned)f2b(e1) << 16);
            const unsigned p23 = (unsigned)f2b(e2) | ((unsigned)f2b(e3) << 16);
            *reinterpret_cast<unsigned*>(&Pbuf[head][c][t * 16 + 4 * g])     = p01;
            *reinterpret_cast<unsigned*>(&Pbuf[head][c][t * 16 + 4 * g + 2]) = p23;
        }

        {
            const uint2 p01 = *reinterpret_cast<const uint2*>(&Pbuf[head][c][8 * g]);
            const uint2 p23 = *reinterpret_cast<const uint2*>(&Pbuf[head][c][8 * g + 4]);
            const int4 pv = make_int4((int)p01.x, (int)p01.y, (int)p23.x, (int)p23.y);
            const bf16x8 pfrag = __builtin_bit_cast(bf16x8, pv);
#pragma unroll
            for (int j = 0; j < 4; ++j) {
                const uint2 v01 = *reinterpret_cast<const uint2*>(&Vt[head][16 * j + c][8 * g]);
                const uint2 v23 = *reinterpret_cast<const uint2*>(&Vt[head][16 * j + c][8 * g + 4]);
                const int4 vv = make_int4((int)v01.x, (int)v01.y, (int)v23.x, (int)v23.y);
                const bf16x8 vfrag = __builtin_bit_cast(bf16x8, vv);
                oacc[j] = __builtin_amdgcn_mfma_f32_16x16x32_bf16(pfrag, vfrag, oacc[j], 0, 0, 0);
            }
        }
    }

    ssum += __shfl_xor(ssum, 16);
    ssum += __shfl_xor(ssum, 32);
    if (l < 16) ssum_lds[head][c] = ssum;
    const f32x4 sums4 = *reinterpret_cast<const f32x4*>(&ssum_lds[head][4 * g]);

    const int orow = pd * (HHH * WWW) + (h0 + g) * WWW + w0;
#pragma unroll
    for (int r = 0; r < 4; ++r) {
        const float inv = 1.0f / sums4[r];
        u16* base = attnc + (size_t)(orow + r) * 512 + head * HDIM;
#pragma unroll
        for (int j = 0; j < 4; ++j)
            base[16 * j + c] = f2b(oacc[j][r] * inv);
    }
}

// ---------------------------------------------------------------------------
extern "C" void kernel_launch(void* const* d_in, const int* in_sizes, int n_in,
                              void* d_out, int out_size, void* d_ws, size_t ws_size,
                              hipStream_t stream)
{
    const float* x      = (const float*)d_in[0];
    const float* w_qkv  = (const float*)d_in[1];
    const float* b_qkv  = (const float*)d_in[2];
    const float* w_proj = (const float*)d_in[3];
    const float* b_proj = (const float*)d_in[4];
    float* out = (float*)d_out;

    u16* qkvb   = (u16*)d_ws;                         // [27648][1536]
    u16* attnc  = qkvb  + (size_t)NPOS * 1536;        // [27648][512] bf16
    u16* xb     = attnc + (size_t)NPOS * 512;         // [27648][512]
    u16* wqkvT  = xb    + (size_t)NPOS * 512;         // [1536][512]
    u16* wprojT = wqkvT + (size_t)1536 * 512;         // [512][512]

    cvt_x_bf16<<<(NPOS * 512 / 4) / 256, 256, 0, stream>>>(x, xb, NPOS * 512 / 4);
    cvt_wqkvT<<<(1536 * 512) / 256, 256, 0, stream>>>(w_qkv, wqkvT);
    cvt_wprojT<<<(512 * 512) / 256, 256, 0, stream>>>(w_proj, wprojT);

    // 1) qkv = x @ w_qkv + b_qkv  (bf16, K=512); grid 2592 = 8*324, nx=12
    gemm_bf16_mfma<<<(1536 / 128) * (NPOS / 128), 256, 0, stream>>>(
        xb, 512, wqkvT, 512, b_qkv, 512, qkvb, 1536, 1, 1536 / 128);

    // 2) attention -> bf16 [NPOS][512]
    na3d_mfma<<<NPOS / 16, 512, 0, stream>>>(qkvb, attnc);

    // 3) out = attn @ w_proj + b_proj  (bf16, K=512); grid 864 = 8*108, nx=4
    gemm_bf16_mfma<<<(512 / 128) * (NPOS / 128), 256, 0, stream>>>(
        attnc, 512, wprojT, 512, b_proj, 512, out, 512, 0, 512 / 128);
}